// Round 9
// baseline (283.396 us; speedup 1.0000x reference)
//
#include <hip/hip_runtime.h>
#include <stdint.h>

#define N_NODES 30000
#define N_EDGES 300000
#define BN_EPS  1e-5f
#define NEG_SLOPE 0.2f

typedef __attribute__((ext_vector_type(8))) short          s16x8;
typedef __attribute__((ext_vector_type(8))) unsigned short u16x8;
typedef __attribute__((ext_vector_type(4))) float          f32x4;

__device__ __forceinline__ float b2f(unsigned int u) { return __uint_as_float(u << 16); }
__device__ __forceinline__ unsigned short f2b(float f) {
    unsigned int u = __float_as_uint(f);
    return (unsigned short)((u + 0x7fffu + ((u >> 16) & 1u)) >> 16);
}
__device__ __forceinline__ float lrelu(float a) { return fmaxf(a, NEG_SLOPE * a); }

// ---------------- L2 warm kernels ----------------
// 512 blocks; blockIdx%8 ~ XCD (round-robin, m09). Each XCD's 64 blocks jointly
// stream the whole array -> populates every XCD's private L2 at streaming BW.
__global__ void __launch_bounds__(256) k_warm2(const uint4* __restrict__ p1, int n1,
                                               const uint4* __restrict__ p2, int n2,
                                               unsigned int* __restrict__ sink) {
    int s = blockIdx.x >> 3;
    unsigned int a = 0;
    for (int i = s * 256 + threadIdx.x; i < n1; i += 16384) {
        uint4 v = p1[i]; a ^= v.x ^ v.y ^ v.z ^ v.w;
    }
    if (p2)
        for (int i = s * 256 + threadIdx.x; i < n2; i += 16384) {
            uint4 v = p2[i]; a ^= v.x ^ v.y ^ v.z ^ v.w;
        }
    sink[blockIdx.x] = a;
}

// warm one 128B half-stripe of xb ([N][256B] rows): bytes [q*128, q*128+128) of each row
__global__ void __launch_bounds__(256) k_warm_h(const uint4* __restrict__ p, int q,
                                                unsigned int* __restrict__ sink) {
    int s = blockIdx.x >> 3;
    unsigned int a = 0;
    for (int i = s * 256 + threadIdx.x; i < 240000; i += 16384) {
        int r = i >> 3, c = i & 7;
        uint4 v = p[r * 16 + q * 8 + c];
        a ^= v.x ^ v.y ^ v.z ^ v.w;
    }
    sink[blockIdx.x] = a;
}

// ---------------- prep: zero counters/stats/out + bf16 conversions + GAT vecs ----------------
__global__ void k_prep(int* __restrict__ cnt, float* __restrict__ stats, float* __restrict__ outz,
                       const float* __restrict__ x, unsigned short* __restrict__ xb,
                       const float* __restrict__ W1l, const float* __restrict__ W1r,
                       const float* __restrict__ W2l, const float* __restrict__ W2r,
                       const float* __restrict__ Wg,
                       unsigned short* __restrict__ t1l, unsigned short* __restrict__ t1r,
                       unsigned short* __restrict__ t2l, unsigned short* __restrict__ t2r,
                       unsigned short* __restrict__ btf,
                       const float* __restrict__ att_src, const float* __restrict__ att_dst,
                       float* __restrict__ vsrc, float* __restrict__ vdst) {
    int b = blockIdx.x, tid = threadIdx.x;
    if (b < 118) {
        int i = b * 256 + tid;
        if (i < N_NODES) cnt[i] = 0;
        if (i < 1344) stats[i] = 0.f;
        if (b == 0 && tid < 64) outz[tid] = 0.f;
    } else if (b < 1118) {
        for (int i = (b - 118) * 256 + tid; i < N_NODES * 128 / 4; i += 256000) {
            float4 v = ((const float4*)x)[i];
            unsigned int lo = f2b(v.x) | ((unsigned int)f2b(v.y) << 16);
            unsigned int hi = f2b(v.z) | ((unsigned int)f2b(v.w) << 16);
            ((uint2*)xb)[i] = make_uint2(lo, hi);
        }
    } else if (b < 1566) {
        int i = (b - 1118) * 256 + tid;
        if (i >= 114688) return;
        if (i >= 98304) {
            int j = i - 98304;
            int n = j >> 8, r = j & 255;
            int h = r >> 6, k = r & 63;
            btf[j] = f2b(Wg[k * 256 + h * 64 + n] * 0.25f);
            return;
        }
        const float* S; unsigned short* D; int K, NN, off;
        if (i < 32768)      { S = W1l; D = t1l; K = 128; NN = 256; off = 0; }
        else if (i < 65536) { S = W1r; D = t1r; K = 128; NN = 256; off = 32768; }
        else if (i < 81920) { S = W2l; D = t2l; K = 256; NN = 64;  off = 65536; }
        else                { S = W2r; D = t2r; K = 256; NN = 64;  off = 81920; }
        int j = i - off;
        int k = j / NN, n = j % NN;
        D[n * K + k] = f2b(S[j]);
    } else {
        int h = tid >> 6, k = tid & 63;
        float s = 0.f, d = 0.f;
        for (int dd = 0; dd < 64; ++dd) {
            float w = Wg[k * 256 + h * 64 + dd];
            s += w * att_src[h * 64 + dd];
            d += w * att_dst[h * 64 + dd];
        }
        vsrc[h * 64 + k] = s;
        vdst[h * 64 + k] = d;
    }
}

// ---------------- CSR build ----------------
__global__ void k_count(const int* __restrict__ dst, int* __restrict__ cnt) {
    int e = blockIdx.x * 256 + threadIdx.x;
    if (e < N_EDGES) atomicAdd(&cnt[dst[e]], 1);
}

__global__ void k_scan1(const int* __restrict__ cnt, int* __restrict__ rowptr, int* __restrict__ bsums) {
    __shared__ int s[256];
    int tid = threadIdx.x;
    int idx = blockIdx.x * 256 + tid;
    int val = (idx < N_NODES) ? cnt[idx] : 0;
    s[tid] = val; __syncthreads();
    for (int o = 1; o < 256; o <<= 1) {
        int add = (tid >= o) ? s[tid - o] : 0;
        __syncthreads();
        s[tid] += add;
        __syncthreads();
    }
    if (idx < N_NODES) rowptr[idx] = s[tid] - val;
    if (tid == 255) bsums[blockIdx.x] = s[255];
}

// merged scan2+scan3: each block computes the block-prefix from bsums itself
__global__ void k_scan3(int* __restrict__ rowptr, const int* __restrict__ bsums, int* __restrict__ cnt) {
    __shared__ int ls[128];
    int tid = threadIdx.x;
    if (tid < 128) ls[tid] = (tid < 118) ? bsums[tid] : 0;
    __syncthreads();
    for (int o = 1; o < 128; o <<= 1) {
        int add = (tid < 128 && tid >= o) ? ls[tid - o] : 0;
        __syncthreads();
        if (tid < 128) ls[tid] += add;
        __syncthreads();
    }
    int ex = (blockIdx.x == 0) ? 0 : ls[blockIdx.x - 1];
    int idx = blockIdx.x * 256 + tid;
    if (idx < N_NODES) { rowptr[idx] += ex; cnt[idx] = 0; }
    if (idx == 0) rowptr[N_NODES] = N_EDGES;
}

__global__ void k_fill(const int* __restrict__ srcA, const int* __restrict__ dstA,
                       const int* __restrict__ rowptr, int* __restrict__ cnt, int* __restrict__ col) {
    int e = blockIdx.x * 256 + threadIdx.x;
    if (e < N_EDGES) {
        int d = dstA[e];
        int pos = rowptr[d] + atomicAdd(&cnt[d], 1);
        col[pos] = srcA[e];
    }
}

// ---------------- SAGE-1 mean aggregation, half-row pass (warmed L2 gather) ----------------
// pass q gathers input cols [q*64, q*64+64) -> writes agg1b cols [q*64, q*64+64)
__global__ void __launch_bounds__(256) k_sage_agg_h(const unsigned short* __restrict__ X,
                                                    const int* __restrict__ rowptr,
                                                    const int* __restrict__ col,
                                                    unsigned short* __restrict__ out, int q) {
    int lane = threadIdx.x & 63;
    int i = (blockIdx.x << 2) + (threadIdx.x >> 6);
    if (i >= N_NODES) return;
    int b = rowptr[i], e = rowptr[i + 1];
    int base = q * 64 + lane;
    float aA = 0.f, aB = 0.f, aC = 0.f, aD = 0.f;
    int p = b;
    for (; p + 4 <= e; p += 4) {
        int j0 = __builtin_nontemporal_load(col + p);
        int j1 = __builtin_nontemporal_load(col + p + 1);
        int j2 = __builtin_nontemporal_load(col + p + 2);
        int j3 = __builtin_nontemporal_load(col + p + 3);
        aA += b2f(X[(size_t)j0 * 128 + base]);
        aB += b2f(X[(size_t)j1 * 128 + base]);
        aC += b2f(X[(size_t)j2 * 128 + base]);
        aD += b2f(X[(size_t)j3 * 128 + base]);
    }
    for (; p < e; ++p) {
        int j = __builtin_nontemporal_load(col + p);
        aA += b2f(X[(size_t)j * 128 + base]);
    }
    float inv = 1.f / fmaxf((float)(e - b), 1.f);
    __builtin_nontemporal_store(f2b((aA + aB + aC + aD) * inv), &out[(size_t)i * 128 + base]);
}

// ---------------- MFMA dual GEMM with optional fused BN-on-A / column stats / split-write ----------------
template<bool BF16OUT, bool BN_A, bool STATS>
__global__ void __launch_bounds__(256) k_mgemm(const unsigned short* __restrict__ A1,
                                               const unsigned short* __restrict__ Bt1, int K1,
                                               const unsigned short* __restrict__ A2,
                                               const unsigned short* __restrict__ Bt2, int K2,
                                               const float* __restrict__ bias,
                                               void* __restrict__ Cv, unsigned short* __restrict__ Cv2,
                                               int M, int NN,
                                               const float* __restrict__ bn_sum,
                                               const float* __restrict__ bn_sq,
                                               const float* __restrict__ bn_g,
                                               const float* __restrict__ bn_be,
                                               float* __restrict__ stS, float* __restrict__ stQ) {
    __shared__ unsigned short As[64 * 32];
    __shared__ unsigned short Bs[64 * 32];
    __shared__ float bnAl[256], bnBl[256];
    int tid = threadIdx.x;
    int w = tid >> 6, l = tid & 63;
    int mBase = blockIdx.x * 64, nBase = blockIdx.y * 64;
    f32x4 acc[4] = {};

    if constexpr (BN_A) {   // inline finstats (K1 == 256)
        float mu = bn_sum[tid] * (1.f / N_NODES);
        float var = bn_sq[tid] * (1.f / N_NODES) - mu * mu;
        float a = bn_g[tid] * rsqrtf(var + BN_EPS);
        bnAl[tid] = a;
        bnBl[tid] = bn_be[tid] - a * mu;
        __syncthreads();
    }

    auto lds_off = [](int row, int col_bf16) -> int {
        return (row * 64 + col_bf16 * 2) ^ ((row & 7) << 4);
    };
    int srow = tid >> 2;
    int schunk = (tid & 3) << 3;
    int s_w_off = lds_off(srow, schunk);
    int kgrp = (l >> 4) << 3;
    int a_off = lds_off(w * 16 + (l & 15), kgrp);
    int b_off[4];
    #pragma unroll
    for (int c = 0; c < 4; ++c) b_off[c] = lds_off(c * 16 + (l & 15), kgrp);

    for (int pair = 0; pair < 2; ++pair) {
        const unsigned short* A  = pair ? A2 : A1;
        const unsigned short* Bt = pair ? Bt2 : Bt1;
        int K = pair ? K2 : K1;
        if (K == 0) break;
        for (int k0 = 0; k0 < K; k0 += 32) {
            u16x8 av = {};
            int arow = mBase + srow;
            if (arow < M) {
                av = *(const u16x8*)&A[(size_t)arow * K + k0 + schunk];
                if constexpr (BN_A) {
                    const float* pa = &bnAl[k0 + schunk];
                    const float* pb = &bnBl[k0 + schunk];
                    #pragma unroll
                    for (int e2 = 0; e2 < 8; ++e2) {
                        float f = fmaxf(b2f(av[e2]) * pa[e2] + pb[e2], 0.f);
                        av[e2] = f2b(f);
                    }
                }
            }
            u16x8 bv = *(const u16x8*)&Bt[(size_t)(nBase + srow) * K + k0 + schunk];
            *(u16x8*)((char*)As + s_w_off) = av;
            *(u16x8*)((char*)Bs + s_w_off) = bv;
            __syncthreads();
            s16x8 a = *(const s16x8*)((const char*)As + a_off);
            #pragma unroll
            for (int c = 0; c < 4; ++c) {
                s16x8 bfr = *(const s16x8*)((const char*)Bs + b_off[c]);
                acc[c] = __builtin_amdgcn_mfma_f32_16x16x32_bf16(a, bfr, acc[c], 0, 0, 0);
            }
            __syncthreads();
        }
    }

    float* lst = (float*)As;  // LDS free after last barrier
    if constexpr (STATS) {
        if (tid < 128) lst[tid] = 0.f;
        __syncthreads();
    }
    int colb = l & 15;
    int rbase = (l >> 4) << 2;
    #pragma unroll
    for (int c = 0; c < 4; ++c) {
        int gcol = nBase + c * 16 + colb;
        float bi = bias ? bias[gcol] : 0.f;
        float s_ = 0.f, q_ = 0.f;
        #pragma unroll
        for (int r = 0; r < 4; ++r) {
            int grow = mBase + w * 16 + rbase + r;
            if (grow < M) {
                float v = acc[c][r] + bi;
                if constexpr (BF16OUT) {
                    unsigned short v16 = f2b(v);
                    if (Cv2) {
                        if (gcol < 64) ((unsigned short*)Cv)[(size_t)grow * 64 + gcol] = v16;
                        else           Cv2[(size_t)grow * 64 + gcol - 64] = v16;
                    } else {
                        ((unsigned short*)Cv)[(size_t)grow * NN + gcol] = v16;
                    }
                } else {
                    ((float*)Cv)[(size_t)grow * NN + gcol] = v;
                }
                if constexpr (STATS) { s_ += v; q_ += v * v; }
            }
        }
        if constexpr (STATS) {
            s_ += __shfl_xor(s_, 16); s_ += __shfl_xor(s_, 32);
            q_ += __shfl_xor(q_, 16); q_ += __shfl_xor(q_, 32);
            if (l < 16) {
                atomicAdd(&lst[c * 16 + l], s_);
                atomicAdd(&lst[64 + c * 16 + l], q_);
            }
        }
    }
    if constexpr (STATS) {
        __syncthreads();
        if (tid < 64) {
            atomicAdd(&stS[nBase + tid], lst[tid]);
            atomicAdd(&stQ[nBase + tid], lst[64 + tid]);
        }
    }
}

// ---------------- final fused GEMM: out[col] += (1/N) * sum_rows relu(A@Btf + bg) ----------------
__global__ void __launch_bounds__(256) k_mgemm_mean(const unsigned short* __restrict__ A,
                                                    const unsigned short* __restrict__ Bt,
                                                    const float* __restrict__ bg,
                                                    float* __restrict__ out, int M) {
    __shared__ unsigned short As[64 * 32];
    __shared__ unsigned short Bs[64 * 32];
    __shared__ float lds_cols[64];
    int tid = threadIdx.x;
    int w = tid >> 6, l = tid & 63;
    int mBase = blockIdx.x * 64;
    if (tid < 64) lds_cols[tid] = 0.f;
    f32x4 acc[4] = {};

    auto lds_off = [](int row, int col_bf16) -> int {
        return (row * 64 + col_bf16 * 2) ^ ((row & 7) << 4);
    };
    int srow = tid >> 2;
    int schunk = (tid & 3) << 3;
    int s_w_off = lds_off(srow, schunk);
    int kgrp = (l >> 4) << 3;
    int a_off = lds_off(w * 16 + (l & 15), kgrp);
    int b_off[4];
    #pragma unroll
    for (int c = 0; c < 4; ++c) b_off[c] = lds_off(c * 16 + (l & 15), kgrp);

    const int K = 256;
    for (int k0 = 0; k0 < K; k0 += 32) {
        u16x8 av = {};
        int arow = mBase + srow;
        if (arow < M) av = *(const u16x8*)&A[(size_t)arow * K + k0 + schunk];
        u16x8 bv = *(const u16x8*)&Bt[(size_t)srow * K + k0 + schunk];
        *(u16x8*)((char*)As + s_w_off) = av;
        *(u16x8*)((char*)Bs + s_w_off) = bv;
        __syncthreads();
        s16x8 a = *(const s16x8*)((const char*)As + a_off);
        #pragma unroll
        for (int c = 0; c < 4; ++c) {
            s16x8 bfr = *(const s16x8*)((const char*)Bs + b_off[c]);
            acc[c] = __builtin_amdgcn_mfma_f32_16x16x32_bf16(a, bfr, acc[c], 0, 0, 0);
        }
        __syncthreads();
    }

    int colb = l & 15;
    int rbase = (l >> 4) << 2;
    #pragma unroll
    for (int c = 0; c < 4; ++c) {
        int gcol = c * 16 + colb;
        float bi = bg[gcol];
        float sc = 0.f;
        #pragma unroll
        for (int r = 0; r < 4; ++r) {
            int grow = mBase + w * 16 + rbase + r;
            if (grow < M) sc += fmaxf(acc[c][r] + bi, 0.f);
        }
        sc += __shfl_xor(sc, 16);
        sc += __shfl_xor(sc, 32);
        if (l < 16) atomicAdd(&lds_cols[c * 16 + l], sc);
    }
    __syncthreads();
    if (tid < 64) atomicAdd(out + tid, lds_cols[tid] * (1.f / N_NODES));
}

// ---------------- SAGE-2 epilogue: h2 = mean_j z2[j] + b2l + r2_i (warmed z2, NT streams) ----------------
__global__ void __launch_bounds__(256) k_sage_add(const unsigned short* __restrict__ z2,
                                                  const unsigned short* __restrict__ r2,
                                                  const int* __restrict__ rowptr,
                                                  const int* __restrict__ col,
                                                  const float* __restrict__ b2l,
                                                  float* __restrict__ h2,
                                                  float* __restrict__ stS, float* __restrict__ stQ) {
    __shared__ float ls[128];
    int tid = threadIdx.x;
    if (tid < 128) ls[tid] = 0.f;
    __syncthreads();
    int lane = tid & 63;
    int wid = tid >> 6;
    float bl = b2l[lane];
    float s_ = 0.f, q_ = 0.f;
    for (int i = blockIdx.x * 4 + wid; i < N_NODES; i += gridDim.x * 4) {
        int b = rowptr[i], e = rowptr[i + 1];
        float aA = 0.f, aB = 0.f;
        int p = b;
        for (; p + 4 <= e; p += 4) {
            int j0 = __builtin_nontemporal_load(col + p);
            int j1 = __builtin_nontemporal_load(col + p + 1);
            int j2 = __builtin_nontemporal_load(col + p + 2);
            int j3 = __builtin_nontemporal_load(col + p + 3);
            float v0 = b2f(z2[(size_t)j0 * 64 + lane]);
            float v1 = b2f(z2[(size_t)j1 * 64 + lane]);
            float v2 = b2f(z2[(size_t)j2 * 64 + lane]);
            float v3 = b2f(z2[(size_t)j3 * 64 + lane]);
            aA += v0 + v2;
            aB += v1 + v3;
        }
        for (; p < e; ++p) aA += b2f(z2[(size_t)__builtin_nontemporal_load(col + p) * 64 + lane]);
        float inv = 1.f / fmaxf((float)(e - b), 1.f);
        float v = (aA + aB) * inv + bl + b2f(__builtin_nontemporal_load(r2 + (size_t)i * 64 + lane));
        __builtin_nontemporal_store(v, &h2[(size_t)i * 64 + lane]);
        s_ += v; q_ += v * v;
    }
    atomicAdd(&ls[lane], s_);
    atomicAdd(&ls[64 + lane], q_);
    __syncthreads();
    if (tid < 64) {
        atomicAdd(&stS[tid], ls[tid]);
        atomicAdd(&stQ[tid], ls[64 + tid]);
    }
}

// ---------------- attn2: inline BN coeffs + BN+relu+cast h2 -> h2b + GAT logits ----------------
__global__ void __launch_bounds__(256) k_attn2(const float* __restrict__ h2,
                                               const float* __restrict__ sum2,
                                               const float* __restrict__ sq2,
                                               const float* __restrict__ g2,
                                               const float* __restrict__ be2,
                                               const float* __restrict__ vsrc,
                                               const float* __restrict__ vdst,
                                               unsigned short* __restrict__ h2b,
                                               float* __restrict__ att) {
    int tid = threadIdx.x;
    int lane = tid & 63;
    int wid = tid >> 6;
    float mu = sum2[lane] * (1.f / N_NODES);
    float var = sq2[lane] * (1.f / N_NODES) - mu * mu;
    float a2 = g2[lane] * rsqrtf(var + BN_EPS);
    float b2v = be2[lane] - a2 * mu;
    float vs0 = vsrc[lane], vs1 = vsrc[64 + lane], vs2 = vsrc[128 + lane], vs3 = vsrc[192 + lane];
    float vd0 = vdst[lane], vd1 = vdst[64 + lane], vd2 = vdst[128 + lane], vd3 = vdst[192 + lane];
    for (int i = blockIdx.x * 4 + wid; i < N_NODES; i += gridDim.x * 4) {
        float v = fmaxf(__builtin_nontemporal_load(h2 + (size_t)i * 64 + lane) * a2 + b2v, 0.f);
        h2b[(size_t)i * 64 + lane] = f2b(v);
        float s0 = v * vs0, s1 = v * vs1, s2 = v * vs2, s3 = v * vs3;
        float d0 = v * vd0, d1 = v * vd1, d2 = v * vd2, d3 = v * vd3;
        #pragma unroll
        for (int o = 32; o; o >>= 1) {
            s0 += __shfl_xor(s0, o); s1 += __shfl_xor(s1, o);
            s2 += __shfl_xor(s2, o); s3 += __shfl_xor(s3, o);
            d0 += __shfl_xor(d0, o); d1 += __shfl_xor(d1, o);
            d2 += __shfl_xor(d2, o); d3 += __shfl_xor(d3, o);
        }
        if (lane == 0) {
            float4* ap = (float4*)(att + (size_t)i * 8);
            ap[0] = make_float4(s0, s1, s2, s3);
            ap[1] = make_float4(d0, d1, d2, d3);
        }
    }
}

// ---------------- GAT aggregate: plain-exp softmax (warmed h2b+att, NT streams) ----------------
__global__ void __launch_bounds__(256) k_gat2(const unsigned short* __restrict__ h2b,
                                              const float* __restrict__ att,
                                              const int* __restrict__ rowptr,
                                              const int* __restrict__ col,
                                              unsigned short* __restrict__ oagg) {
    int tid = threadIdx.x;
    int lane = tid & 63;
    int gw = (blockIdx.x << 2) + (tid >> 6);
    int stride = gridDim.x << 2;
    for (int i = gw; i < N_NODES; i += stride) {
        int b = rowptr[i], e = rowptr[i + 1];
        float4 ai = *(const float4*)(att + (size_t)i * 8);
        float4 ad = *(const float4*)(att + (size_t)i * 8 + 4);
        float hv = b2f(h2b[(size_t)i * 64 + lane]);
        float w0 = __expf(lrelu(ai.x + ad.x));
        float w1 = __expf(lrelu(ai.y + ad.y));
        float w2 = __expf(lrelu(ai.z + ad.z));
        float w3 = __expf(lrelu(ai.w + ad.w));
        float s0 = w0, s1 = w1, s2 = w2, s3 = w3;
        float a0 = w0 * hv, a1 = w1 * hv, a2 = w2 * hv, a3 = w3 * hv;
        int p = b;
        for (; p + 2 <= e; p += 2) {
            int j0 = __builtin_nontemporal_load(col + p);
            int j1 = __builtin_nontemporal_load(col + p + 1);
            float4 aj0 = *(const float4*)(att + (size_t)j0 * 8);
            float4 aj1 = *(const float4*)(att + (size_t)j1 * 8);
            float hj0 = b2f(h2b[(size_t)j0 * 64 + lane]);
            float hj1 = b2f(h2b[(size_t)j1 * 64 + lane]);
            float e00 = __expf(lrelu(aj0.x + ad.x));
            float e01 = __expf(lrelu(aj0.y + ad.y));
            float e02 = __expf(lrelu(aj0.z + ad.z));
            float e03 = __expf(lrelu(aj0.w + ad.w));
            float e10 = __expf(lrelu(aj1.x + ad.x));
            float e11 = __expf(lrelu(aj1.y + ad.y));
            float e12 = __expf(lrelu(aj1.z + ad.z));
            float e13 = __expf(lrelu(aj1.w + ad.w));
            s0 += e00 + e10; a0 = fmaf(e00, hj0, fmaf(e10, hj1, a0));
            s1 += e01 + e11; a1 = fmaf(e01, hj0, fmaf(e11, hj1, a1));
            s2 += e02 + e12; a2 = fmaf(e02, hj0, fmaf(e12, hj1, a2));
            s3 += e03 + e13; a3 = fmaf(e03, hj0, fmaf(e13, hj1, a3));
        }
        if (p < e) {
            int j = __builtin_nontemporal_load(col + p);
            float4 aj = *(const float4*)(att + (size_t)j * 8);
            float hj = b2f(h2b[(size_t)j * 64 + lane]);
            float e0 = __expf(lrelu(aj.x + ad.x));
            float e1 = __expf(lrelu(aj.y + ad.y));
            float e2 = __expf(lrelu(aj.z + ad.z));
            float e3 = __expf(lrelu(aj.w + ad.w));
            s0 += e0; a0 = fmaf(e0, hj, a0);
            s1 += e1; a1 = fmaf(e1, hj, a1);
            s2 += e2; a2 = fmaf(e2, hj, a2);
            s3 += e3; a3 = fmaf(e3, hj, a3);
        }
        unsigned short* op = oagg + (size_t)i * 256 + lane;
        __builtin_nontemporal_store(f2b(a0 / s0), op);
        __builtin_nontemporal_store(f2b(a1 / s1), op + 64);
        __builtin_nontemporal_store(f2b(a2 / s2), op + 128);
        __builtin_nontemporal_store(f2b(a3 / s3), op + 192);
    }
}

// ---------------- launch ----------------
extern "C" void kernel_launch(void* const* d_in, const int* in_sizes, int n_in,
                              void* d_out, int out_size, void* d_ws, size_t ws_size,
                              hipStream_t stream) {
    const float* x       = (const float*)d_in[0];
    const int*   ei      = (const int*)d_in[1];
    const float* W1l     = (const float*)d_in[2];
    const float* b1l     = (const float*)d_in[3];
    const float* W1r     = (const float*)d_in[4];
    const float* W2l     = (const float*)d_in[5];
    const float* b2l     = (const float*)d_in[6];
    const float* W2r     = (const float*)d_in[7];
    const float* g1      = (const float*)d_in[8];
    const float* be1     = (const float*)d_in[9];
    const float* g2      = (const float*)d_in[10];
    const float* be2     = (const float*)d_in[11];
    const float* Wg      = (const float*)d_in[12];
    const float* att_src = (const float*)d_in[13];
    const float* att_dst = (const float*)d_in[14];
    const float* bg      = (const float*)d_in[15];
    float* out = (float*)d_out;

    char* p = (char*)d_ws;
    auto alloc = [&](size_t bytes) -> char* {
        char* q = p;
        p += (bytes + 255) & ~(size_t)255;
        return q;
    };
    int*   cnt    = (int*)alloc((size_t)N_NODES * 4);
    float* stats  = (float*)alloc(1856 * 4);
    int*   rowptr = (int*)alloc((size_t)(N_NODES + 1) * 4);
    int*   bsums  = (int*)alloc(256 * 4);
    unsigned int* wsink = (unsigned int*)alloc(512 * 4);
    int*   col    = (int*)alloc((size_t)N_EDGES * 4);
    unsigned short* xb    = (unsigned short*)alloc((size_t)N_NODES * 128 * 2);  // 7.68MB
    unsigned short* agg1b = (unsigned short*)alloc((size_t)N_NODES * 128 * 2);  // 7.68MB, contiguous after xb
    unsigned short* h1b = (unsigned short*)alloc((size_t)N_NODES * 256 * 2);    // 15.36MB
    float* h2   = (float*)alloc((size_t)N_NODES * 64 * 4);                      // 7.68MB
    unsigned short* h2b = (unsigned short*)alloc((size_t)N_NODES * 64 * 2);     // 3.84MB
    float* att  = (float*)alloc((size_t)N_NODES * 8 * 4);                       // 0.96MB
    unsigned short* w1lt = (unsigned short*)alloc(128 * 256 * 2);
    unsigned short* w1rt = (unsigned short*)alloc(128 * 256 * 2);
    unsigned short* w2lt = (unsigned short*)alloc(256 * 64 * 2);   // [w2lt|w2rt] contiguous [128][256]
    unsigned short* w2rt = (unsigned short*)alloc(256 * 64 * 2);
    unsigned short* btf  = (unsigned short*)alloc(64 * 256 * 2);

    // aliases (lifetimes): z2/r2 in agg1b (dead after mgemm1); oagg spans xb+agg1b (dead by k_gat2)
    unsigned short* z2 = agg1b;                       // 3.84MB — warmed L2 gather target
    unsigned short* r2 = agg1b + (size_t)N_NODES * 64;
    unsigned short* oagg = xb;

    float* sum1 = stats;        float* sq1 = stats + 256;
    float* sum2 = stats + 1024; float* sq2 = stats + 1088;
    float* vsrc = stats + 1344; float* vdst = stats + 1600;

    const int* srcA = ei;
    const int* dstA = ei + N_EDGES;

    // prep (zero cnt/stats/out, cvt x, cvt+transpose weights, attention vecs)
    k_prep<<<1567, 256, 0, stream>>>(cnt, stats, out, x, xb, W1l, W1r, W2l, W2r, Wg,
                                     w1lt, w1rt, w2lt, w2rt, btf, att_src, att_dst, vsrc, vdst);
    // CSR build
    k_count<<<1172, 256, 0, stream>>>(dstA, cnt);
    k_scan1<<<118, 256, 0, stream>>>(cnt, rowptr, bsums);
    k_scan3<<<118, 256, 0, stream>>>(rowptr, bsums, cnt);
    k_fill<<<1172, 256, 0, stream>>>(srcA, dstA, rowptr, cnt, col);

    // SAGE layer 1: two warmed half-row gather passes -> dual GEMM (+stats)
    k_warm_h<<<512, 256, 0, stream>>>((const uint4*)xb, 0, wsink);
    k_sage_agg_h<<<7500, 256, 0, stream>>>(xb, rowptr, col, agg1b, 0);
    k_warm_h<<<512, 256, 0, stream>>>((const uint4*)xb, 1, wsink);
    k_sage_agg_h<<<7500, 256, 0, stream>>>(xb, rowptr, col, agg1b, 1);
    k_mgemm<true, false, true><<<dim3(469, 4), 256, 0, stream>>>(
        agg1b, w1lt, 128, xb, w1rt, 128, b1l, h1b, nullptr, N_NODES, 256,
        nullptr, nullptr, nullptr, nullptr, sum1, sq1);

    // SAGE layer 2: GEMM (inline BN1 on A, split z2/r2) -> warm z2 -> gather-add (+stats)
    k_mgemm<true, true, false><<<dim3(469, 2), 256, 0, stream>>>(
        h1b, w2lt, 256, nullptr, nullptr, 0, nullptr, z2, r2, N_NODES, 128,
        sum1, sq1, g1, be1, nullptr, nullptr);
    k_warm2<<<512, 256, 0, stream>>>((const uint4*)z2, 240000, nullptr, 0, wsink);
    k_sage_add<<<1875, 256, 0, stream>>>(z2, r2, rowptr, col, b2l, h2, sum2, sq2);

    // GAT: inline BN2+logits -> warm h2b+att -> softmax aggregate -> projection+mean GEMM
    k_attn2<<<1875, 256, 0, stream>>>(h2, sum2, sq2, g2, be2, vsrc, vdst, h2b, att);
    k_warm2<<<512, 256, 0, stream>>>((const uint4*)h2b, 240000, (const uint4*)att, 60000, wsink);
    k_gat2<<<2048, 256, 0, stream>>>(h2b, att, rowptr, col, oagg);
    k_mgemm_mean<<<469, 256, 0, stream>>>(oagg, btf, bg, out, N_NODES);
}

// Round 10
// 252.565 us; speedup vs baseline: 1.1221x; 1.1221x over previous
//
#include <hip/hip_runtime.h>
#include <stdint.h>

#define N_NODES 30000
#define N_EDGES 300000
#define BN_EPS  1e-5f
#define NEG_SLOPE 0.2f

typedef __attribute__((ext_vector_type(8))) short          s16x8;
typedef __attribute__((ext_vector_type(8))) unsigned short u16x8;
typedef __attribute__((ext_vector_type(4))) float          f32x4;

__device__ __forceinline__ float b2f(unsigned int u) { return __uint_as_float(u << 16); }
__device__ __forceinline__ unsigned short f2b(float f) {
    unsigned int u = __float_as_uint(f);
    return (unsigned short)((u + 0x7fffu + ((u >> 16) & 1u)) >> 16);
}
// fp8 e4m3fn (OCP) encode/decode, RNE, denorm-correct, clamp to +-448
__device__ __forceinline__ unsigned int f2q(float f) {
    unsigned int s = (__float_as_uint(f) >> 31) << 7;
    float af = fminf(fabsf(f), 448.f);
    if (af < 0.015625f) {
        int m = (int)rintf(af * 512.f);
        return s | (unsigned int)m;   // m==8 naturally encodes e=1,m=0
    }
    unsigned int b = __float_as_uint(af);
    b += 0x7FFFFu + ((b >> 20) & 1u);
    unsigned int e = (b >> 23) - 120u;
    unsigned int m = (b >> 20) & 7u;
    if (e > 15u) { e = 15u; m = 6u; }
    return s | (e << 3) | m;
}
__device__ __forceinline__ float q2f(unsigned int u) {
    unsigned int em = u & 0x7f;
    float nrm = __uint_as_float((((em >> 3) + 120u) << 23) | ((em & 7u) << 20));
    float den = (float)em * 0.001953125f;
    float mag = (em >= 8u) ? nrm : den;
    return (u & 0x80u) ? -mag : mag;
}
__device__ __forceinline__ float lrelu(float a) { return fmaxf(a, NEG_SLOPE * a); }

// ---------------- prep: zero counters/stats/out + conversions (bf16 + fp8) + GAT vecs ----------------
__global__ void k_prep(int* __restrict__ cnt, float* __restrict__ stats, float* __restrict__ outz,
                       const float* __restrict__ x, unsigned short* __restrict__ xb,
                       unsigned char* __restrict__ xq,
                       const float* __restrict__ W1l, const float* __restrict__ W1r,
                       const float* __restrict__ W2l, const float* __restrict__ W2r,
                       const float* __restrict__ Wg,
                       unsigned short* __restrict__ t1l, unsigned short* __restrict__ t1r,
                       unsigned short* __restrict__ t2l, unsigned short* __restrict__ t2r,
                       unsigned short* __restrict__ btf,
                       const float* __restrict__ att_src, const float* __restrict__ att_dst,
                       float* __restrict__ vsrc, float* __restrict__ vdst) {
    int b = blockIdx.x, tid = threadIdx.x;
    if (b < 118) {
        int i = b * 256 + tid;
        if (i < N_NODES) cnt[i] = 0;
        if (i < 1856) stats[i] = 0.f;
        if (b == 0 && tid < 64) outz[tid] = 0.f;
    } else if (b < 1118) {
        for (int i = (b - 118) * 256 + tid; i < N_NODES * 128 / 4; i += 256000) {
            float4 v = ((const float4*)x)[i];
            unsigned int lo = f2b(v.x) | ((unsigned int)f2b(v.y) << 16);
            unsigned int hi = f2b(v.z) | ((unsigned int)f2b(v.w) << 16);
            ((uint2*)xb)[i] = make_uint2(lo, hi);
            unsigned int q = f2q(v.x) | (f2q(v.y) << 8) | (f2q(v.z) << 16) | (f2q(v.w) << 24);
            ((unsigned int*)xq)[i] = q;
        }
    } else if (b < 1566) {
        int i = (b - 1118) * 256 + tid;
        if (i >= 114688) return;
        if (i >= 98304) {
            int j = i - 98304;
            int n = j >> 8, r = j & 255;
            int h = r >> 6, k = r & 63;
            btf[j] = f2b(Wg[k * 256 + h * 64 + n] * 0.25f);
            return;
        }
        const float* S; unsigned short* D; int K, NN, off;
        if (i < 32768)      { S = W1l; D = t1l; K = 128; NN = 256; off = 0; }
        else if (i < 65536) { S = W1r; D = t1r; K = 128; NN = 256; off = 32768; }
        else if (i < 81920) { S = W2l; D = t2l; K = 256; NN = 64;  off = 65536; }
        else                { S = W2r; D = t2r; K = 256; NN = 64;  off = 81920; }
        int j = i - off;
        int k = j / NN, n = j % NN;
        D[n * K + k] = f2b(S[j]);
    } else {
        int h = tid >> 6, k = tid & 63;
        float s = 0.f, d = 0.f;
        for (int dd = 0; dd < 64; ++dd) {
            float w = Wg[k * 256 + h * 64 + dd];
            s += w * att_src[h * 64 + dd];
            d += w * att_dst[h * 64 + dd];
        }
        vsrc[h * 64 + k] = s;
        vdst[h * 64 + k] = d;
    }
}

// ---------------- CSR build ----------------
__global__ void k_count(const int* __restrict__ dst, int* __restrict__ cnt) {
    int e = blockIdx.x * 256 + threadIdx.x;
    if (e < N_EDGES) atomicAdd(&cnt[dst[e]], 1);
}

__global__ void k_scan1(const int* __restrict__ cnt, int* __restrict__ rowptr, int* __restrict__ bsums) {
    __shared__ int s[256];
    int tid = threadIdx.x;
    int idx = blockIdx.x * 256 + tid;
    int val = (idx < N_NODES) ? cnt[idx] : 0;
    s[tid] = val; __syncthreads();
    for (int o = 1; o < 256; o <<= 1) {
        int add = (tid >= o) ? s[tid - o] : 0;
        __syncthreads();
        s[tid] += add;
        __syncthreads();
    }
    if (idx < N_NODES) rowptr[idx] = s[tid] - val;
    if (tid == 255) bsums[blockIdx.x] = s[255];
}

// merged scan2+scan3
__global__ void k_scan3(int* __restrict__ rowptr, const int* __restrict__ bsums, int* __restrict__ cnt) {
    __shared__ int ls[128];
    int tid = threadIdx.x;
    if (tid < 128) ls[tid] = (tid < 118) ? bsums[tid] : 0;
    __syncthreads();
    for (int o = 1; o < 128; o <<= 1) {
        int add = (tid < 128 && tid >= o) ? ls[tid - o] : 0;
        __syncthreads();
        if (tid < 128) ls[tid] += add;
        __syncthreads();
    }
    int ex = (blockIdx.x == 0) ? 0 : ls[blockIdx.x - 1];
    int idx = blockIdx.x * 256 + tid;
    if (idx < N_NODES) { rowptr[idx] += ex; cnt[idx] = 0; }
    if (idx == 0) rowptr[N_NODES] = N_EDGES;
}

__global__ void k_fill(const int* __restrict__ srcA, const int* __restrict__ dstA,
                       const int* __restrict__ rowptr, int* __restrict__ cnt, int* __restrict__ col) {
    int e = blockIdx.x * 256 + threadIdx.x;
    if (e < N_EDGES) {
        int d = dstA[e];
        int pos = rowptr[d] + atomicAdd(&cnt[d], 1);
        col[pos] = srcA[e];
    }
}

// ---------------- SAGE-1 mean aggregation: gather fp8 rows (128B/edge), bf16 out ----------------
__global__ void __launch_bounds__(256) k_sage_agg_q(const unsigned char* __restrict__ Xq,
                                                    const int* __restrict__ rowptr,
                                                    const int* __restrict__ col,
                                                    unsigned short* __restrict__ out) {
    int lane = threadIdx.x & 63;
    int i = (blockIdx.x << 2) + (threadIdx.x >> 6);
    if (i >= N_NODES) return;
    int b = rowptr[i], e = rowptr[i + 1];
    float aA0 = 0.f, aA1 = 0.f, aB0 = 0.f, aB1 = 0.f;
    int p = b;
    for (; p + 4 <= e; p += 4) {
        int j0 = __builtin_nontemporal_load(col + p);
        int j1 = __builtin_nontemporal_load(col + p + 1);
        int j2 = __builtin_nontemporal_load(col + p + 2);
        int j3 = __builtin_nontemporal_load(col + p + 3);
        unsigned int u0 = *(const unsigned short*)(Xq + (size_t)j0 * 128 + lane * 2);
        unsigned int u1 = *(const unsigned short*)(Xq + (size_t)j1 * 128 + lane * 2);
        unsigned int u2 = *(const unsigned short*)(Xq + (size_t)j2 * 128 + lane * 2);
        unsigned int u3 = *(const unsigned short*)(Xq + (size_t)j3 * 128 + lane * 2);
        aA0 += q2f(u0 & 0xffu) + q2f(u2 & 0xffu);
        aA1 += q2f(u0 >> 8)    + q2f(u2 >> 8);
        aB0 += q2f(u1 & 0xffu) + q2f(u3 & 0xffu);
        aB1 += q2f(u1 >> 8)    + q2f(u3 >> 8);
    }
    for (; p < e; ++p) {
        int j = __builtin_nontemporal_load(col + p);
        unsigned int u = *(const unsigned short*)(Xq + (size_t)j * 128 + lane * 2);
        aA0 += q2f(u & 0xffu);
        aA1 += q2f(u >> 8);
    }
    float inv = 1.f / fmaxf((float)(e - b), 1.f);
    unsigned int o = f2b((aA0 + aB0) * inv) | ((unsigned int)f2b((aA1 + aB1) * inv) << 16);
    __builtin_nontemporal_store(o, (unsigned int*)(out + (size_t)i * 128 + lane * 2));
}

// ---------------- MFMA dual GEMM; OUTM: 1 = bf16 out, 2 = split (fp8 zq | bf16 r2) ----------------
template<int OUTM, bool BN_A, bool STATS>
__global__ void __launch_bounds__(256) k_mgemm(const unsigned short* __restrict__ A1,
                                               const unsigned short* __restrict__ Bt1, int K1,
                                               const unsigned short* __restrict__ A2,
                                               const unsigned short* __restrict__ Bt2, int K2,
                                               const float* __restrict__ bias,
                                               void* __restrict__ Cv,
                                               unsigned char* __restrict__ Czq,
                                               unsigned short* __restrict__ Cr2,
                                               int M, int NN,
                                               const float* __restrict__ bn_sum,
                                               const float* __restrict__ bn_sq,
                                               const float* __restrict__ bn_g,
                                               const float* __restrict__ bn_be,
                                               float* __restrict__ stS, float* __restrict__ stQ) {
    __shared__ unsigned short As[64 * 32];
    __shared__ unsigned short Bs[64 * 32];
    __shared__ float bnAl[256], bnBl[256];
    int tid = threadIdx.x;
    int w = tid >> 6, l = tid & 63;
    int mBase = blockIdx.x * 64, nBase = blockIdx.y * 64;
    f32x4 acc[4] = {};

    if constexpr (BN_A) {   // inline finstats (K1 == 256)
        float mu = bn_sum[tid] * (1.f / N_NODES);
        float var = bn_sq[tid] * (1.f / N_NODES) - mu * mu;
        float a = bn_g[tid] * rsqrtf(var + BN_EPS);
        bnAl[tid] = a;
        bnBl[tid] = bn_be[tid] - a * mu;
        __syncthreads();
    }

    auto lds_off = [](int row, int col_bf16) -> int {
        return (row * 64 + col_bf16 * 2) ^ ((row & 7) << 4);
    };
    int srow = tid >> 2;
    int schunk = (tid & 3) << 3;
    int s_w_off = lds_off(srow, schunk);
    int kgrp = (l >> 4) << 3;
    int a_off = lds_off(w * 16 + (l & 15), kgrp);
    int b_off[4];
    #pragma unroll
    for (int c = 0; c < 4; ++c) b_off[c] = lds_off(c * 16 + (l & 15), kgrp);

    for (int pair = 0; pair < 2; ++pair) {
        const unsigned short* A  = pair ? A2 : A1;
        const unsigned short* Bt = pair ? Bt2 : Bt1;
        int K = pair ? K2 : K1;
        if (K == 0) break;
        for (int k0 = 0; k0 < K; k0 += 32) {
            u16x8 av = {};
            int arow = mBase + srow;
            if (arow < M) {
                av = *(const u16x8*)&A[(size_t)arow * K + k0 + schunk];
                if constexpr (BN_A) {
                    const float* pa = &bnAl[k0 + schunk];
                    const float* pb = &bnBl[k0 + schunk];
                    #pragma unroll
                    for (int e2 = 0; e2 < 8; ++e2) {
                        float f = fmaxf(b2f(av[e2]) * pa[e2] + pb[e2], 0.f);
                        av[e2] = f2b(f);
                    }
                }
            }
            u16x8 bv = *(const u16x8*)&Bt[(size_t)(nBase + srow) * K + k0 + schunk];
            *(u16x8*)((char*)As + s_w_off) = av;
            *(u16x8*)((char*)Bs + s_w_off) = bv;
            __syncthreads();
            s16x8 a = *(const s16x8*)((const char*)As + a_off);
            #pragma unroll
            for (int c = 0; c < 4; ++c) {
                s16x8 bfr = *(const s16x8*)((const char*)Bs + b_off[c]);
                acc[c] = __builtin_amdgcn_mfma_f32_16x16x32_bf16(a, bfr, acc[c], 0, 0, 0);
            }
            __syncthreads();
        }
    }

    float* lst = (float*)As;  // LDS free after last barrier
    if constexpr (STATS) {
        if (tid < 128) lst[tid] = 0.f;
        __syncthreads();
    }
    int colb = l & 15;
    int rbase = (l >> 4) << 2;
    #pragma unroll
    for (int c = 0; c < 4; ++c) {
        int gcol = nBase + c * 16 + colb;
        float bi = bias ? bias[gcol] : 0.f;
        float s_ = 0.f, q_ = 0.f;
        #pragma unroll
        for (int r = 0; r < 4; ++r) {
            int grow = mBase + w * 16 + rbase + r;
            if (grow < M) {
                float v = acc[c][r] + bi;
                if constexpr (OUTM == 1) {
                    ((unsigned short*)Cv)[(size_t)grow * NN + gcol] = f2b(v);
                } else {
                    if (gcol < 64) Czq[(size_t)grow * 64 + gcol] = (unsigned char)f2q(v);
                    else           Cr2[(size_t)grow * 64 + gcol - 64] = f2b(v);
                }
                if constexpr (STATS) { s_ += v; q_ += v * v; }
            }
        }
        if constexpr (STATS) {
            s_ += __shfl_xor(s_, 16); s_ += __shfl_xor(s_, 32);
            q_ += __shfl_xor(q_, 16); q_ += __shfl_xor(q_, 32);
            if (l < 16) {
                atomicAdd(&lst[c * 16 + l], s_);
                atomicAdd(&lst[64 + c * 16 + l], q_);
            }
        }
    }
    if constexpr (STATS) {
        __syncthreads();
        if (tid < 64) {
            atomicAdd(&stS[nBase + tid], lst[tid]);
            atomicAdd(&stQ[nBase + tid], lst[64 + tid]);
        }
    }
}

// ---------------- final fused GEMM: out[col] += (1/N) * sum_rows relu(A@Btf + bg) ----------------
__global__ void __launch_bounds__(256) k_mgemm_mean(const unsigned short* __restrict__ A,
                                                    const unsigned short* __restrict__ Bt,
                                                    const float* __restrict__ bg,
                                                    float* __restrict__ out, int M) {
    __shared__ unsigned short As[64 * 32];
    __shared__ unsigned short Bs[64 * 32];
    __shared__ float lds_cols[64];
    int tid = threadIdx.x;
    int w = tid >> 6, l = tid & 63;
    int mBase = blockIdx.x * 64;
    if (tid < 64) lds_cols[tid] = 0.f;
    f32x4 acc[4] = {};

    auto lds_off = [](int row, int col_bf16) -> int {
        return (row * 64 + col_bf16 * 2) ^ ((row & 7) << 4);
    };
    int srow = tid >> 2;
    int schunk = (tid & 3) << 3;
    int s_w_off = lds_off(srow, schunk);
    int kgrp = (l >> 4) << 3;
    int a_off = lds_off(w * 16 + (l & 15), kgrp);
    int b_off[4];
    #pragma unroll
    for (int c = 0; c < 4; ++c) b_off[c] = lds_off(c * 16 + (l & 15), kgrp);

    const int K = 256;
    for (int k0 = 0; k0 < K; k0 += 32) {
        u16x8 av = {};
        int arow = mBase + srow;
        if (arow < M) av = *(const u16x8*)&A[(size_t)arow * K + k0 + schunk];
        u16x8 bv = *(const u16x8*)&Bt[(size_t)srow * K + k0 + schunk];
        *(u16x8*)((char*)As + s_w_off) = av;
        *(u16x8*)((char*)Bs + s_w_off) = bv;
        __syncthreads();
        s16x8 a = *(const s16x8*)((const char*)As + a_off);
        #pragma unroll
        for (int c = 0; c < 4; ++c) {
            s16x8 bfr = *(const s16x8*)((const char*)Bs + b_off[c]);
            acc[c] = __builtin_amdgcn_mfma_f32_16x16x32_bf16(a, bfr, acc[c], 0, 0, 0);
        }
        __syncthreads();
    }

    int colb = l & 15;
    int rbase = (l >> 4) << 2;
    #pragma unroll
    for (int c = 0; c < 4; ++c) {
        int gcol = c * 16 + colb;
        float bi = bg[gcol];
        float sc = 0.f;
        #pragma unroll
        for (int r = 0; r < 4; ++r) {
            int grow = mBase + w * 16 + rbase + r;
            if (grow < M) sc += fmaxf(acc[c][r] + bi, 0.f);
        }
        sc += __shfl_xor(sc, 16);
        sc += __shfl_xor(sc, 32);
        if (l < 16) atomicAdd(&lds_cols[c * 16 + l], sc);
    }
    __syncthreads();
    if (tid < 64) atomicAdd(out + tid, lds_cols[tid] * (1.f / N_NODES));
}

// ---------------- SAGE-2 epilogue: h2 = mean_j zq[j] + b2l + r2_i (fp8 gather, bf16 out) ----------------
__global__ void __launch_bounds__(256) k_sage_add(const unsigned char* __restrict__ zq,
                                                  const unsigned short* __restrict__ r2,
                                                  const int* __restrict__ rowptr,
                                                  const int* __restrict__ col,
                                                  const float* __restrict__ b2l,
                                                  unsigned short* __restrict__ h2,
                                                  float* __restrict__ stS, float* __restrict__ stQ) {
    __shared__ float ls[128];
    int tid = threadIdx.x;
    if (tid < 128) ls[tid] = 0.f;
    __syncthreads();
    int lane = tid & 63;
    int wid = tid >> 6;
    float bl = b2l[lane];
    float s_ = 0.f, q_ = 0.f;
    for (int i = blockIdx.x * 4 + wid; i < N_NODES; i += gridDim.x * 4) {
        int b = rowptr[i], e = rowptr[i + 1];
        float aA = 0.f, aB = 0.f;
        int p = b;
        for (; p + 4 <= e; p += 4) {
            int j0 = __builtin_nontemporal_load(col + p);
            int j1 = __builtin_nontemporal_load(col + p + 1);
            int j2 = __builtin_nontemporal_load(col + p + 2);
            int j3 = __builtin_nontemporal_load(col + p + 3);
            float v0 = q2f(zq[(size_t)j0 * 64 + lane]);
            float v1 = q2f(zq[(size_t)j1 * 64 + lane]);
            float v2 = q2f(zq[(size_t)j2 * 64 + lane]);
            float v3 = q2f(zq[(size_t)j3 * 64 + lane]);
            aA += v0 + v2;
            aB += v1 + v3;
        }
        for (; p < e; ++p) aA += q2f(zq[(size_t)__builtin_nontemporal_load(col + p) * 64 + lane]);
        float inv = 1.f / fmaxf((float)(e - b), 1.f);
        float v = (aA + aB) * inv + bl + b2f(__builtin_nontemporal_load(r2 + (size_t)i * 64 + lane));
        __builtin_nontemporal_store(f2b(v), &h2[(size_t)i * 64 + lane]);
        s_ += v; q_ += v * v;
    }
    atomicAdd(&ls[lane], s_);
    atomicAdd(&ls[64 + lane], q_);
    __syncthreads();
    if (tid < 64) {
        atomicAdd(&stS[tid], ls[tid]);
        atomicAdd(&stQ[tid], ls[64 + tid]);
    }
}

// ---------------- attn2: inline BN coeffs + BN+relu h2 -> h2q (fp8) + GAT logits ----------------
__global__ void __launch_bounds__(256) k_attn2(const unsigned short* __restrict__ h2,
                                               const float* __restrict__ sum2,
                                               const float* __restrict__ sq2,
                                               const float* __restrict__ g2,
                                               const float* __restrict__ be2,
                                               const float* __restrict__ vsrc,
                                               const float* __restrict__ vdst,
                                               unsigned char* __restrict__ h2q,
                                               float* __restrict__ att) {
    int tid = threadIdx.x;
    int lane = tid & 63;
    int wid = tid >> 6;
    float mu = sum2[lane] * (1.f / N_NODES);
    float var = sq2[lane] * (1.f / N_NODES) - mu * mu;
    float a2 = g2[lane] * rsqrtf(var + BN_EPS);
    float b2v = be2[lane] - a2 * mu;
    float vs0 = vsrc[lane], vs1 = vsrc[64 + lane], vs2 = vsrc[128 + lane], vs3 = vsrc[192 + lane];
    float vd0 = vdst[lane], vd1 = vdst[64 + lane], vd2 = vdst[128 + lane], vd3 = vdst[192 + lane];
    for (int i = blockIdx.x * 4 + wid; i < N_NODES; i += gridDim.x * 4) {
        float v = fmaxf(b2f(__builtin_nontemporal_load(h2 + (size_t)i * 64 + lane)) * a2 + b2v, 0.f);
        h2q[(size_t)i * 64 + lane] = (unsigned char)f2q(v);
        float s0 = v * vs0, s1 = v * vs1, s2 = v * vs2, s3 = v * vs3;
        float d0 = v * vd0, d1 = v * vd1, d2 = v * vd2, d3 = v * vd3;
        #pragma unroll
        for (int o = 32; o; o >>= 1) {
            s0 += __shfl_xor(s0, o); s1 += __shfl_xor(s1, o);
            s2 += __shfl_xor(s2, o); s3 += __shfl_xor(s3, o);
            d0 += __shfl_xor(d0, o); d1 += __shfl_xor(d1, o);
            d2 += __shfl_xor(d2, o); d3 += __shfl_xor(d3, o);
        }
        if (lane == 0) {
            float4* ap = (float4*)(att + (size_t)i * 8);
            ap[0] = make_float4(s0, s1, s2, s3);
            ap[1] = make_float4(d0, d1, d2, d3);
        }
    }
}

// ---------------- GAT aggregate: plain-exp softmax over fp8 h2q gather ----------------
__global__ void __launch_bounds__(256) k_gat2(const unsigned char* __restrict__ h2q,
                                              const float* __restrict__ att,
                                              const int* __restrict__ rowptr,
                                              const int* __restrict__ col,
                                              unsigned short* __restrict__ oagg) {
    int tid = threadIdx.x;
    int lane = tid & 63;
    int gw = (blockIdx.x << 2) + (tid >> 6);
    int stride = gridDim.x << 2;
    for (int i = gw; i < N_NODES; i += stride) {
        int b = rowptr[i], e = rowptr[i + 1];
        float4 ai = *(const float4*)(att + (size_t)i * 8);
        float4 ad = *(const float4*)(att + (size_t)i * 8 + 4);
        float hv = q2f(h2q[(size_t)i * 64 + lane]);
        float w0 = __expf(lrelu(ai.x + ad.x));
        float w1 = __expf(lrelu(ai.y + ad.y));
        float w2 = __expf(lrelu(ai.z + ad.z));
        float w3 = __expf(lrelu(ai.w + ad.w));
        float s0 = w0, s1 = w1, s2 = w2, s3 = w3;
        float a0 = w0 * hv, a1 = w1 * hv, a2 = w2 * hv, a3 = w3 * hv;
        int p = b;
        for (; p + 2 <= e; p += 2) {
            int j0 = __builtin_nontemporal_load(col + p);
            int j1 = __builtin_nontemporal_load(col + p + 1);
            float4 aj0 = *(const float4*)(att + (size_t)j0 * 8);
            float4 aj1 = *(const float4*)(att + (size_t)j1 * 8);
            float hj0 = q2f(h2q[(size_t)j0 * 64 + lane]);
            float hj1 = q2f(h2q[(size_t)j1 * 64 + lane]);
            float e00 = __expf(lrelu(aj0.x + ad.x));
            float e01 = __expf(lrelu(aj0.y + ad.y));
            float e02 = __expf(lrelu(aj0.z + ad.z));
            float e03 = __expf(lrelu(aj0.w + ad.w));
            float e10 = __expf(lrelu(aj1.x + ad.x));
            float e11 = __expf(lrelu(aj1.y + ad.y));
            float e12 = __expf(lrelu(aj1.z + ad.z));
            float e13 = __expf(lrelu(aj1.w + ad.w));
            s0 += e00 + e10; a0 = fmaf(e00, hj0, fmaf(e10, hj1, a0));
            s1 += e01 + e11; a1 = fmaf(e01, hj0, fmaf(e11, hj1, a1));
            s2 += e02 + e12; a2 = fmaf(e02, hj0, fmaf(e12, hj1, a2));
            s3 += e03 + e13; a3 = fmaf(e03, hj0, fmaf(e13, hj1, a3));
        }
        if (p < e) {
            int j = __builtin_nontemporal_load(col + p);
            float4 aj = *(const float4*)(att + (size_t)j * 8);
            float hj = q2f(h2q[(size_t)j * 64 + lane]);
            float e0 = __expf(lrelu(aj.x + ad.x));
            float e1 = __expf(lrelu(aj.y + ad.y));
            float e2 = __expf(lrelu(aj.z + ad.z));
            float e3 = __expf(lrelu(aj.w + ad.w));
            s0 += e0; a0 = fmaf(e0, hj, a0);
            s1 += e1; a1 = fmaf(e1, hj, a1);
            s2 += e2; a2 = fmaf(e2, hj, a2);
            s3 += e3; a3 = fmaf(e3, hj, a3);
        }
        unsigned short* op = oagg + (size_t)i * 256 + lane;
        __builtin_nontemporal_store(f2b(a0 / s0), op);
        __builtin_nontemporal_store(f2b(a1 / s1), op + 64);
        __builtin_nontemporal_store(f2b(a2 / s2), op + 128);
        __builtin_nontemporal_store(f2b(a3 / s3), op + 192);
    }
}

// ---------------- launch ----------------
extern "C" void kernel_launch(void* const* d_in, const int* in_sizes, int n_in,
                              void* d_out, int out_size, void* d_ws, size_t ws_size,
                              hipStream_t stream) {
    const float* x       = (const float*)d_in[0];
    const int*   ei      = (const int*)d_in[1];
    const float* W1l     = (const float*)d_in[2];
    const float* b1l     = (const float*)d_in[3];
    const float* W1r     = (const float*)d_in[4];
    const float* W2l     = (const float*)d_in[5];
    const float* b2l     = (const float*)d_in[6];
    const float* W2r     = (const float*)d_in[7];
    const float* g1      = (const float*)d_in[8];
    const float* be1     = (const float*)d_in[9];
    const float* g2      = (const float*)d_in[10];
    const float* be2     = (const float*)d_in[11];
    const float* Wg      = (const float*)d_in[12];
    const float* att_src = (const float*)d_in[13];
    const float* att_dst = (const float*)d_in[14];
    const float* bg      = (const float*)d_in[15];
    float* out = (float*)d_out;

    char* p = (char*)d_ws;
    auto alloc = [&](size_t bytes) -> char* {
        char* q = p;
        p += (bytes + 255) & ~(size_t)255;
        return q;
    };
    int*   cnt    = (int*)alloc((size_t)N_NODES * 4);
    float* stats  = (float*)alloc(1856 * 4);
    int*   rowptr = (int*)alloc((size_t)(N_NODES + 1) * 4);
    int*   bsums  = (int*)alloc(256 * 4);
    int*   col    = (int*)alloc((size_t)N_EDGES * 4);
    unsigned short* xb  = (unsigned short*)alloc((size_t)N_NODES * 128 * 2);   // 7.68MB (GEMM A2)
    unsigned char*  xq  = (unsigned char*)alloc((size_t)N_NODES * 128);        // 3.84MB (gather, fp8)
    unsigned short* agg1b = (unsigned short*)alloc((size_t)N_NODES * 128 * 2); // 7.68MB
    unsigned short* h1b = (unsigned short*)alloc((size_t)N_NODES * 256 * 2);   // 15.36MB
    unsigned char*  zq  = (unsigned char*)alloc((size_t)N_NODES * 64);         // 1.92MB (gather, fp8)
    unsigned short* r2  = (unsigned short*)alloc((size_t)N_NODES * 64 * 2);    // 3.84MB
    unsigned short* h2  = (unsigned short*)alloc((size_t)N_NODES * 64 * 2);    // 3.84MB (bf16)
    unsigned char*  h2q = (unsigned char*)alloc((size_t)N_NODES * 64);         // 1.92MB (gather, fp8)
    float* att  = (float*)alloc((size_t)N_NODES * 8 * 4);                      // 0.96MB
    unsigned short* w1lt = (unsigned short*)alloc(128 * 256 * 2);
    unsigned short* w1rt = (unsigned short*)alloc(128 * 256 * 2);
    unsigned short* w2lt = (unsigned short*)alloc(256 * 64 * 2);  // [w2lt|w2rt] contiguous [128][256]
    unsigned short* w2rt = (unsigned short*)alloc(256 * 64 * 2);
    unsigned short* btf  = (unsigned short*)alloc(64 * 256 * 2);

    // oagg [N][256] bf16 (15.36MB) aliases xb+xq+agg1b head (all dead before k_gat2;
    // sizes are 256B multiples so the three allocs are contiguous)
    unsigned short* oagg = xb;

    float* sum1 = stats;        float* sq1 = stats + 256;
    float* sum2 = stats + 1024; float* sq2 = stats + 1088;
    float* vsrc = stats + 1344; float* vdst = stats + 1600;

    const int* srcA = ei;
    const int* dstA = ei + N_EDGES;

    // prep (zero cnt/stats/out, cvt x -> bf16+fp8, cvt+transpose weights, attention vecs)
    k_prep<<<1567, 256, 0, stream>>>(cnt, stats, out, x, xb, xq, W1l, W1r, W2l, W2r, Wg,
                                     w1lt, w1rt, w2lt, w2rt, btf, att_src, att_dst, vsrc, vdst);
    // CSR build
    k_count<<<1172, 256, 0, stream>>>(dstA, cnt);
    k_scan1<<<118, 256, 0, stream>>>(cnt, rowptr, bsums);
    k_scan3<<<118, 256, 0, stream>>>(rowptr, bsums, cnt);
    k_fill<<<1172, 256, 0, stream>>>(srcA, dstA, rowptr, cnt, col);

    // SAGE layer 1: fp8 gather-mean -> dual GEMM (bf16 out + fused column stats)
    k_sage_agg_q<<<7500, 256, 0, stream>>>(xq, rowptr, col, agg1b);
    k_mgemm<1, false, true><<<dim3(469, 4), 256, 0, stream>>>(
        agg1b, w1lt, 128, xb, w1rt, 128, b1l, h1b, nullptr, nullptr, N_NODES, 256,
        nullptr, nullptr, nullptr, nullptr, sum1, sq1);

    // SAGE layer 2: GEMM (inline BN1 on A, split fp8 zq | bf16 r2) -> fp8 gather-add (+stats)
    k_mgemm<2, true, false><<<dim3(469, 2), 256, 0, stream>>>(
        h1b, w2lt, 256, nullptr, nullptr, 0, nullptr, nullptr, zq, r2, N_NODES, 128,
        sum1, sq1, g1, be1, nullptr, nullptr);
    k_sage_add<<<1875, 256, 0, stream>>>(zq, r2, rowptr, col, b2l, h2, sum2, sq2);

    // GAT: inline BN2 + logits + fp8 h2q -> softmax aggregate -> projection+mean GEMM
    k_attn2<<<1875, 256, 0, stream>>>(h2, sum2, sq2, g2, be2, vsrc, vdst, h2q, att);
    k_gat2<<<2048, 256, 0, stream>>>(h2q, att, rowptr, col, oagg);
    k_mgemm_mean<<<469, 256, 0, stream>>>(oagg, btf, bg, out, N_NODES);
}

// Round 11
// 203.359 us; speedup vs baseline: 1.3936x; 1.2420x over previous
//
#include <hip/hip_runtime.h>
#include <stdint.h>

#define N_NODES 30000
#define N_EDGES 300000
#define BN_EPS  1e-5f
#define NEG_SLOPE 0.2f

typedef __attribute__((ext_vector_type(8))) short          s16x8;
typedef __attribute__((ext_vector_type(8))) unsigned short u16x8;
typedef __attribute__((ext_vector_type(4))) float          f32x4;

__device__ __forceinline__ float b2f(unsigned int u) { return __uint_as_float(u << 16); }
__device__ __forceinline__ unsigned int f2b(float f) {
    unsigned int u = __float_as_uint(f);
    return (u + 0x7fffu + ((u >> 16) & 1u)) >> 16;
}
// fp8 e4m3fn (OCP) encode/decode, RNE, denorm-correct, clamp to +-448
__device__ __forceinline__ unsigned int f2q(float f) {
    unsigned int s = (__float_as_uint(f) >> 31) << 7;
    float af = fminf(fabsf(f), 448.f);
    if (af < 0.015625f) {
        int m = (int)rintf(af * 512.f);
        return s | (unsigned int)m;
    }
    unsigned int b = __float_as_uint(af);
    b += 0x7FFFFu + ((b >> 20) & 1u);
    unsigned int e = (b >> 23) - 120u;
    unsigned int m = (b >> 20) & 7u;
    if (e > 15u) { e = 15u; m = 6u; }
    return s | (e << 3) | m;
}
__device__ __forceinline__ float q2f(unsigned int u) {
    unsigned int em = u & 0x7f;
    float nrm = __uint_as_float((((em >> 3) + 120u) << 23) | ((em & 7u) << 20));
    float den = (float)em * 0.001953125f;
    float mag = (em >= 8u) ? nrm : den;
    return (u & 0x80u) ? -mag : mag;
}
__device__ __forceinline__ float lrelu(float a) { return fmaxf(a, NEG_SLOPE * a); }

// ---------------- prep ----------------
__global__ void k_prep(int* __restrict__ cnt, float* __restrict__ stats, float* __restrict__ outz,
                       const float* __restrict__ x, unsigned short* __restrict__ xb,
                       unsigned char* __restrict__ xq,
                       const float* __restrict__ W1l, const float* __restrict__ W1r,
                       const float* __restrict__ W2l, const float* __restrict__ W2r,
                       const float* __restrict__ Wg,
                       unsigned short* __restrict__ t1l, unsigned short* __restrict__ t1r,
                       unsigned short* __restrict__ t2l, unsigned short* __restrict__ t2r,
                       unsigned short* __restrict__ btf,
                       const float* __restrict__ att_src, const float* __restrict__ att_dst,
                       float* __restrict__ vsrc, float* __restrict__ vdst) {
    int b = blockIdx.x, tid = threadIdx.x;
    if (b < 118) {
        int i = b * 256 + tid;
        if (i < N_NODES) cnt[i] = 0;
        if (i < 3072) stats[i] = 0.f;
        if (b == 0 && tid < 64) outz[tid] = 0.f;
    } else if (b < 1118) {
        for (int i = (b - 118) * 256 + tid; i < N_NODES * 128 / 4; i += 256000) {
            float4 v = ((const float4*)x)[i];
            unsigned int lo = f2b(v.x) | (f2b(v.y) << 16);
            unsigned int hi = f2b(v.z) | (f2b(v.w) << 16);
            ((uint2*)xb)[i] = make_uint2(lo, hi);
            unsigned int q = f2q(v.x) | (f2q(v.y) << 8) | (f2q(v.z) << 16) | (f2q(v.w) << 24);
            ((unsigned int*)xq)[i] = q;
        }
    } else if (b < 1566) {
        int i = (b - 1118) * 256 + tid;
        if (i >= 114688) return;
        if (i >= 98304) {
            int j = i - 98304;
            int n = j >> 8, r = j & 255;
            int h = r >> 6, k = r & 63;
            btf[j] = f2b(Wg[k * 256 + h * 64 + n] * 0.25f);
            return;
        }
        const float* S; unsigned short* D; int K, NN, off;
        if (i < 32768)      { S = W1l; D = t1l; K = 128; NN = 256; off = 0; }
        else if (i < 65536) { S = W1r; D = t1r; K = 128; NN = 256; off = 32768; }
        else if (i < 81920) { S = W2l; D = t2l; K = 256; NN = 64;  off = 65536; }
        else                { S = W2r; D = t2r; K = 256; NN = 64;  off = 81920; }
        int j = i - off;
        int k = j / NN, n = j % NN;
        D[n * K + k] = f2b(S[j]);
    } else {
        int h = tid >> 6, k = tid & 63;
        float s = 0.f, d = 0.f;
        for (int dd = 0; dd < 64; ++dd) {
            float w = Wg[k * 256 + h * 64 + dd];
            s += w * att_src[h * 64 + dd];
            d += w * att_dst[h * 64 + dd];
        }
        vsrc[h * 64 + k] = s;
        vdst[h * 64 + k] = d;
    }
}

// ---------------- CSR build ----------------
__global__ void k_count(const int* __restrict__ dst, int* __restrict__ cnt) {
    int e = blockIdx.x * 256 + threadIdx.x;
    if (e < N_EDGES) atomicAdd(&cnt[dst[e]], 1);
}

__global__ void k_scan1(const int* __restrict__ cnt, int* __restrict__ rowptr, int* __restrict__ bsums) {
    __shared__ int s[256];
    int tid = threadIdx.x;
    int idx = blockIdx.x * 256 + tid;
    int val = (idx < N_NODES) ? cnt[idx] : 0;
    s[tid] = val; __syncthreads();
    for (int o = 1; o < 256; o <<= 1) {
        int add = (tid >= o) ? s[tid - o] : 0;
        __syncthreads();
        s[tid] += add;
        __syncthreads();
    }
    if (idx < N_NODES) rowptr[idx] = s[tid] - val;
    if (tid == 255) bsums[blockIdx.x] = s[255];
}

__global__ void k_scan3(int* __restrict__ rowptr, const int* __restrict__ bsums, int* __restrict__ cnt) {
    __shared__ int ls[128];
    int tid = threadIdx.x;
    if (tid < 128) ls[tid] = (tid < 118) ? bsums[tid] : 0;
    __syncthreads();
    for (int o = 1; o < 128; o <<= 1) {
        int add = (tid < 128 && tid >= o) ? ls[tid - o] : 0;
        __syncthreads();
        if (tid < 128) ls[tid] += add;
        __syncthreads();
    }
    int ex = (blockIdx.x == 0) ? 0 : ls[blockIdx.x - 1];
    int idx = blockIdx.x * 256 + tid;
    if (idx < N_NODES) { rowptr[idx] += ex; cnt[idx] = 0; }
    if (idx == 0) rowptr[N_NODES] = N_EDGES;
}

__global__ void k_fill(const int* __restrict__ srcA, const int* __restrict__ dstA,
                       const int* __restrict__ rowptr, int* __restrict__ cnt, int* __restrict__ col) {
    int e = blockIdx.x * 256 + threadIdx.x;
    if (e < N_EDGES) {
        int d = dstA[e];
        int pos = rowptr[d] + atomicAdd(&cnt[d], 1);
        col[pos] = srcA[e];
    }
}

// ---------------- SAGE-1 aggregation: lane-split 4-edge gathers (fp8 rows, 8 lines/iter) ----------------
__global__ void __launch_bounds__(256) k_sage_agg_q(const unsigned char* __restrict__ Xq,
                                                    const int* __restrict__ rowptr,
                                                    const int* __restrict__ col,
                                                    unsigned short* __restrict__ out) {
    int lane = threadIdx.x & 63;
    int i = (blockIdx.x << 2) + (threadIdx.x >> 6);
    if (i >= N_NODES) return;
    int eg = lane >> 4, fq = lane & 15;
    int b = rowptr[i], e = rowptr[i + 1];
    float a[8] = {};
    int p = b;
    int i0 = p + eg, i1 = p + 4 + eg;
    int j0 = (i0 < e) ? col[i0] : i; float m0 = (i0 < e) ? 1.f : 0.f;
    int j1 = (i1 < e) ? col[i1] : i; float m1 = (i1 < e) ? 1.f : 0.f;
    while (p < e) {
        int i2 = p + 8 + eg, i3 = p + 12 + eg;
        int j2 = (i2 < e) ? col[i2] : i; float m2 = (i2 < e) ? 1.f : 0.f;
        int j3 = (i3 < e) ? col[i3] : i; float m3 = (i3 < e) ? 1.f : 0.f;
        uint2 g0 = *(const uint2*)(Xq + (size_t)j0 * 128 + fq * 8);
        uint2 g1 = *(const uint2*)(Xq + (size_t)j1 * 128 + fq * 8);
        #pragma unroll
        for (int q = 0; q < 4; ++q) {
            a[q]     += m0 * q2f((g0.x >> (q * 8)) & 0xffu) + m1 * q2f((g1.x >> (q * 8)) & 0xffu);
            a[4 + q] += m0 * q2f((g0.y >> (q * 8)) & 0xffu) + m1 * q2f((g1.y >> (q * 8)) & 0xffu);
        }
        j0 = j2; m0 = m2; j1 = j3; m1 = m3; p += 8;
    }
    #pragma unroll
    for (int q = 0; q < 8; ++q) {
        a[q] += __shfl_xor(a[q], 16);
        a[q] += __shfl_xor(a[q], 32);
    }
    if (lane < 16) {
        float inv = 1.f / fmaxf((float)(e - b), 1.f);
        uint4 o;
        o.x = f2b(a[0] * inv) | (f2b(a[1] * inv) << 16);
        o.y = f2b(a[2] * inv) | (f2b(a[3] * inv) << 16);
        o.z = f2b(a[4] * inv) | (f2b(a[5] * inv) << 16);
        o.w = f2b(a[6] * inv) | (f2b(a[7] * inv) << 16);
        *(uint4*)(out + (size_t)i * 128 + fq * 8) = o;
    }
}

// ---------------- MFMA dual GEMM; OUTM: 1 = bf16 out, 2 = split (fp8 zq | bf16 r2) ----------------
// STATS -> 4-replica atomics (replica = blockIdx.x&3); BN_A sums the 4 replicas inline.
template<int OUTM, bool BN_A, bool STATS>
__global__ void __launch_bounds__(256) k_mgemm(const unsigned short* __restrict__ A1,
                                               const unsigned short* __restrict__ Bt1, int K1,
                                               const unsigned short* __restrict__ A2,
                                               const unsigned short* __restrict__ Bt2, int K2,
                                               const float* __restrict__ bias,
                                               void* __restrict__ Cv,
                                               unsigned char* __restrict__ Czq,
                                               unsigned short* __restrict__ Cr2,
                                               int M, int NN,
                                               const float* __restrict__ bn_sum,
                                               const float* __restrict__ bn_sq,
                                               const float* __restrict__ bn_g,
                                               const float* __restrict__ bn_be,
                                               float* __restrict__ stS, float* __restrict__ stQ) {
    __shared__ unsigned short As[64 * 32];
    __shared__ unsigned short Bs[64 * 32];
    __shared__ float bnAl[256], bnBl[256];
    int tid = threadIdx.x;
    int w = tid >> 6, l = tid & 63;
    int mBase = blockIdx.x * 64, nBase = blockIdx.y * 64;
    f32x4 acc[4] = {};

    if constexpr (BN_A) {   // inline finstats from 4 replicas (K1 == 256)
        float su = bn_sum[tid] + bn_sum[256 + tid] + bn_sum[512 + tid] + bn_sum[768 + tid];
        float sq = bn_sq[tid] + bn_sq[256 + tid] + bn_sq[512 + tid] + bn_sq[768 + tid];
        float mu = su * (1.f / N_NODES);
        float var = sq * (1.f / N_NODES) - mu * mu;
        float a = bn_g[tid] * rsqrtf(var + BN_EPS);
        bnAl[tid] = a;
        bnBl[tid] = bn_be[tid] - a * mu;
        __syncthreads();
    }

    auto lds_off = [](int row, int col_bf16) -> int {
        return (row * 64 + col_bf16 * 2) ^ ((row & 7) << 4);
    };
    int srow = tid >> 2;
    int schunk = (tid & 3) << 3;
    int s_w_off = lds_off(srow, schunk);
    int kgrp = (l >> 4) << 3;
    int a_off = lds_off(w * 16 + (l & 15), kgrp);
    int b_off[4];
    #pragma unroll
    for (int c = 0; c < 4; ++c) b_off[c] = lds_off(c * 16 + (l & 15), kgrp);

    for (int pair = 0; pair < 2; ++pair) {
        const unsigned short* A  = pair ? A2 : A1;
        const unsigned short* Bt = pair ? Bt2 : Bt1;
        int K = pair ? K2 : K1;
        if (K == 0) break;
        for (int k0 = 0; k0 < K; k0 += 32) {
            u16x8 av = {};
            int arow = mBase + srow;
            if (arow < M) {
                av = *(const u16x8*)&A[(size_t)arow * K + k0 + schunk];
                if constexpr (BN_A) {
                    const float* pa = &bnAl[k0 + schunk];
                    const float* pb = &bnBl[k0 + schunk];
                    #pragma unroll
                    for (int e2 = 0; e2 < 8; ++e2) {
                        float f = fmaxf(b2f(av[e2]) * pa[e2] + pb[e2], 0.f);
                        av[e2] = (unsigned short)f2b(f);
                    }
                }
            }
            u16x8 bv = *(const u16x8*)&Bt[(size_t)(nBase + srow) * K + k0 + schunk];
            *(u16x8*)((char*)As + s_w_off) = av;
            *(u16x8*)((char*)Bs + s_w_off) = bv;
            __syncthreads();
            s16x8 a = *(const s16x8*)((const char*)As + a_off);
            #pragma unroll
            for (int c = 0; c < 4; ++c) {
                s16x8 bfr = *(const s16x8*)((const char*)Bs + b_off[c]);
                acc[c] = __builtin_amdgcn_mfma_f32_16x16x32_bf16(a, bfr, acc[c], 0, 0, 0);
            }
            __syncthreads();
        }
    }

    float* lst = (float*)As;
    if constexpr (STATS) {
        if (tid < 128) lst[tid] = 0.f;
        __syncthreads();
    }
    int colb = l & 15;
    int rbase = (l >> 4) << 2;
    #pragma unroll
    for (int c = 0; c < 4; ++c) {
        int gcol = nBase + c * 16 + colb;
        float bi = bias ? bias[gcol] : 0.f;
        float s_ = 0.f, q_ = 0.f;
        #pragma unroll
        for (int r = 0; r < 4; ++r) {
            int grow = mBase + w * 16 + rbase + r;
            if (grow < M) {
                float v = acc[c][r] + bi;
                if constexpr (OUTM == 1) {
                    ((unsigned short*)Cv)[(size_t)grow * NN + gcol] = (unsigned short)f2b(v);
                } else {
                    if (gcol < 64) Czq[(size_t)grow * 64 + gcol] = (unsigned char)f2q(v);
                    else           Cr2[(size_t)grow * 64 + gcol - 64] = (unsigned short)f2b(v);
                }
                if constexpr (STATS) { s_ += v; q_ += v * v; }
            }
        }
        if constexpr (STATS) {
            s_ += __shfl_xor(s_, 16); s_ += __shfl_xor(s_, 32);
            q_ += __shfl_xor(q_, 16); q_ += __shfl_xor(q_, 32);
            if (l < 16) {
                atomicAdd(&lst[c * 16 + l], s_);
                atomicAdd(&lst[64 + c * 16 + l], q_);
            }
        }
    }
    if constexpr (STATS) {
        __syncthreads();
        int rep = (blockIdx.x & 3) * 256;
        if (tid < 64) {
            atomicAdd(&stS[rep + nBase + tid], lst[tid]);
            atomicAdd(&stQ[rep + nBase + tid], lst[64 + tid]);
        }
    }
}

// ---------------- final fused GEMM: out[col] += (1/N) * sum_rows relu(A@Btf + bg) ----------------
__global__ void __launch_bounds__(256) k_mgemm_mean(const unsigned short* __restrict__ A,
                                                    const unsigned short* __restrict__ Bt,
                                                    const float* __restrict__ bg,
                                                    float* __restrict__ out, int M) {
    __shared__ unsigned short As[64 * 32];
    __shared__ unsigned short Bs[64 * 32];
    __shared__ float lds_cols[64];
    int tid = threadIdx.x;
    int w = tid >> 6, l = tid & 63;
    int mBase = blockIdx.x * 64;
    if (tid < 64) lds_cols[tid] = 0.f;
    f32x4 acc[4] = {};

    auto lds_off = [](int row, int col_bf16) -> int {
        return (row * 64 + col_bf16 * 2) ^ ((row & 7) << 4);
    };
    int srow = tid >> 2;
    int schunk = (tid & 3) << 3;
    int s_w_off = lds_off(srow, schunk);
    int kgrp = (l >> 4) << 3;
    int a_off = lds_off(w * 16 + (l & 15), kgrp);
    int b_off[4];
    #pragma unroll
    for (int c = 0; c < 4; ++c) b_off[c] = lds_off(c * 16 + (l & 15), kgrp);

    const int K = 256;
    for (int k0 = 0; k0 < K; k0 += 32) {
        u16x8 av = {};
        int arow = mBase + srow;
        if (arow < M) av = *(const u16x8*)&A[(size_t)arow * K + k0 + schunk];
        u16x8 bv = *(const u16x8*)&Bt[(size_t)srow * K + k0 + schunk];
        *(u16x8*)((char*)As + s_w_off) = av;
        *(u16x8*)((char*)Bs + s_w_off) = bv;
        __syncthreads();
        s16x8 a = *(const s16x8*)((const char*)As + a_off);
        #pragma unroll
        for (int c = 0; c < 4; ++c) {
            s16x8 bfr = *(const s16x8*)((const char*)Bs + b_off[c]);
            acc[c] = __builtin_amdgcn_mfma_f32_16x16x32_bf16(a, bfr, acc[c], 0, 0, 0);
        }
        __syncthreads();
    }

    int colb = l & 15;
    int rbase = (l >> 4) << 2;
    #pragma unroll
    for (int c = 0; c < 4; ++c) {
        int gcol = c * 16 + colb;
        float bi = bg[gcol];
        float sc = 0.f;
        #pragma unroll
        for (int r = 0; r < 4; ++r) {
            int grow = mBase + w * 16 + rbase + r;
            if (grow < M) sc += fmaxf(acc[c][r] + bi, 0.f);
        }
        sc += __shfl_xor(sc, 16);
        sc += __shfl_xor(sc, 32);
        if (l < 16) atomicAdd(&lds_cols[c * 16 + l], sc);
    }
    __syncthreads();
    if (tid < 64) atomicAdd(out + tid, lds_cols[tid] * (1.f / N_NODES));
}

// ---------------- SAGE-2 epilogue: lane-split 4-edge fp8 gathers + stats (4 replicas) ----------------
__global__ void __launch_bounds__(256) k_sage_add(const unsigned char* __restrict__ zq,
                                                  const unsigned short* __restrict__ r2,
                                                  const int* __restrict__ rowptr,
                                                  const int* __restrict__ col,
                                                  const float* __restrict__ b2l,
                                                  unsigned short* __restrict__ h2,
                                                  float* __restrict__ stS, float* __restrict__ stQ) {
    __shared__ float ls[128];
    int tid = threadIdx.x;
    if (tid < 128) ls[tid] = 0.f;
    __syncthreads();
    int lane = tid & 63;
    int wid = tid >> 6;
    int eg = lane >> 4, fq = lane & 15;
    float4 blv = ((const float4*)b2l)[fq];
    float sa[4] = {}, qa[4] = {};
    for (int i = blockIdx.x * 4 + wid; i < N_NODES; i += gridDim.x * 4) {
        int b = rowptr[i], e = rowptr[i + 1];
        float a[4] = {};
        int p = b;
        int i0 = p + eg, i1 = p + 4 + eg;
        int j0 = (i0 < e) ? col[i0] : i; float m0 = (i0 < e) ? 1.f : 0.f;
        int j1 = (i1 < e) ? col[i1] : i; float m1 = (i1 < e) ? 1.f : 0.f;
        while (p < e) {
            int i2 = p + 8 + eg, i3 = p + 12 + eg;
            int j2 = (i2 < e) ? col[i2] : i; float m2 = (i2 < e) ? 1.f : 0.f;
            int j3 = (i3 < e) ? col[i3] : i; float m3 = (i3 < e) ? 1.f : 0.f;
            unsigned int g0 = *(const unsigned int*)(zq + (size_t)j0 * 64 + fq * 4);
            unsigned int g1 = *(const unsigned int*)(zq + (size_t)j1 * 64 + fq * 4);
            #pragma unroll
            for (int q = 0; q < 4; ++q)
                a[q] += m0 * q2f((g0 >> (q * 8)) & 0xffu) + m1 * q2f((g1 >> (q * 8)) & 0xffu);
            j0 = j2; m0 = m2; j1 = j3; m1 = m3; p += 8;
        }
        #pragma unroll
        for (int q = 0; q < 4; ++q) {
            a[q] += __shfl_xor(a[q], 16);
            a[q] += __shfl_xor(a[q], 32);
        }
        if (lane < 16) {
            float inv = 1.f / fmaxf((float)(e - b), 1.f);
            uint2 rr = *(const uint2*)(r2 + (size_t)i * 64 + fq * 4);
            float v0 = a[0] * inv + blv.x + b2f(rr.x & 0xffffu);
            float v1 = a[1] * inv + blv.y + b2f(rr.x >> 16);
            float v2 = a[2] * inv + blv.z + b2f(rr.y & 0xffffu);
            float v3 = a[3] * inv + blv.w + b2f(rr.y >> 16);
            uint2 o;
            o.x = f2b(v0) | (f2b(v1) << 16);
            o.y = f2b(v2) | (f2b(v3) << 16);
            *(uint2*)(h2 + (size_t)i * 64 + fq * 4) = o;
            sa[0] += v0; qa[0] += v0 * v0;
            sa[1] += v1; qa[1] += v1 * v1;
            sa[2] += v2; qa[2] += v2 * v2;
            sa[3] += v3; qa[3] += v3 * v3;
        }
    }
    if (lane < 16) {
        #pragma unroll
        for (int q = 0; q < 4; ++q) {
            atomicAdd(&ls[fq * 4 + q], sa[q]);
            atomicAdd(&ls[64 + fq * 4 + q], qa[q]);
        }
    }
    __syncthreads();
    int rep = (blockIdx.x & 3) * 64;
    if (tid < 64) {
        atomicAdd(&stS[rep + tid], ls[tid]);
        atomicAdd(&stQ[rep + tid], ls[64 + tid]);
    }
}

// ---------------- attn2: inline BN coeffs (4 replicas) + BN+relu h2 -> h2q + GAT logits ----------------
__global__ void __launch_bounds__(256) k_attn2(const unsigned short* __restrict__ h2,
                                               const float* __restrict__ sum2,
                                               const float* __restrict__ sq2,
                                               const float* __restrict__ g2,
                                               const float* __restrict__ be2,
                                               const float* __restrict__ vsrc,
                                               const float* __restrict__ vdst,
                                               unsigned char* __restrict__ h2q,
                                               float* __restrict__ att) {
    int tid = threadIdx.x;
    int lane = tid & 63;
    int wid = tid >> 6;
    float su = sum2[lane] + sum2[64 + lane] + sum2[128 + lane] + sum2[192 + lane];
    float sq = sq2[lane] + sq2[64 + lane] + sq2[128 + lane] + sq2[192 + lane];
    float mu = su * (1.f / N_NODES);
    float var = sq * (1.f / N_NODES) - mu * mu;
    float a2 = g2[lane] * rsqrtf(var + BN_EPS);
    float b2v = be2[lane] - a2 * mu;
    float vs0 = vsrc[lane], vs1 = vsrc[64 + lane], vs2 = vsrc[128 + lane], vs3 = vsrc[192 + lane];
    float vd0 = vdst[lane], vd1 = vdst[64 + lane], vd2 = vdst[128 + lane], vd3 = vdst[192 + lane];
    for (int i = blockIdx.x * 4 + wid; i < N_NODES; i += gridDim.x * 4) {
        float v = fmaxf(b2f(__builtin_nontemporal_load(h2 + (size_t)i * 64 + lane)) * a2 + b2v, 0.f);
        h2q[(size_t)i * 64 + lane] = (unsigned char)f2q(v);
        float s0 = v * vs0, s1 = v * vs1, s2 = v * vs2, s3 = v * vs3;
        float d0 = v * vd0, d1 = v * vd1, d2 = v * vd2, d3 = v * vd3;
        #pragma unroll
        for (int o = 32; o; o >>= 1) {
            s0 += __shfl_xor(s0, o); s1 += __shfl_xor(s1, o);
            s2 += __shfl_xor(s2, o); s3 += __shfl_xor(s3, o);
            d0 += __shfl_xor(d0, o); d1 += __shfl_xor(d1, o);
            d2 += __shfl_xor(d2, o); d3 += __shfl_xor(d3, o);
        }
        if (lane == 0) {
            float4* ap = (float4*)(att + (size_t)i * 8);
            ap[0] = make_float4(s0, s1, s2, s3);
            ap[1] = make_float4(d0, d1, d2, d3);
        }
    }
}

// ---------------- GAT aggregate: lane-split 4-edge gathers, per-group exp (4x fewer) ----------------
__global__ void __launch_bounds__(256) k_gat2(const unsigned char* __restrict__ h2q,
                                              const float* __restrict__ att,
                                              const int* __restrict__ rowptr,
                                              const int* __restrict__ col,
                                              unsigned short* __restrict__ oagg) {
    int tid = threadIdx.x;
    int lane = tid & 63;
    int eg = lane >> 4, fq = lane & 15;
    int gw = (blockIdx.x << 2) + (tid >> 6);
    int stride = gridDim.x << 2;
    for (int i = gw; i < N_NODES; i += stride) {
        int b = rowptr[i], e = rowptr[i + 1];
        float4 ai = *(const float4*)(att + (size_t)i * 8);
        float4 ad = *(const float4*)(att + (size_t)i * 8 + 4);
        unsigned int hvg = *(const unsigned int*)(h2q + (size_t)i * 64 + fq * 4);
        float hv[4];
        #pragma unroll
        for (int q = 0; q < 4; ++q) hv[q] = q2f((hvg >> (q * 8)) & 0xffu);
        float wself0 = __expf(lrelu(ai.x + ad.x));
        float wself1 = __expf(lrelu(ai.y + ad.y));
        float wself2 = __expf(lrelu(ai.z + ad.z));
        float wself3 = __expf(lrelu(ai.w + ad.w));
        float sg = (eg == 0) ? 1.f : 0.f;
        float s[4] = { sg * wself0, sg * wself1, sg * wself2, sg * wself3 };
        float acc[4][4];
        #pragma unroll
        for (int q = 0; q < 4; ++q) {
            acc[0][q] = s[0] * hv[q];
            acc[1][q] = s[1] * hv[q];
            acc[2][q] = s[2] * hv[q];
            acc[3][q] = s[3] * hv[q];
        }
        int p = b;
        int i0 = p + eg, i1 = p + 4 + eg;
        int j0 = (i0 < e) ? col[i0] : i; float m0 = (i0 < e) ? 1.f : 0.f;
        int j1 = (i1 < e) ? col[i1] : i; float m1 = (i1 < e) ? 1.f : 0.f;
        while (p < e) {
            int i2 = p + 8 + eg, i3 = p + 12 + eg;
            int j2 = (i2 < e) ? col[i2] : i; float m2 = (i2 < e) ? 1.f : 0.f;
            int j3 = (i3 < e) ? col[i3] : i; float m3 = (i3 < e) ? 1.f : 0.f;
            float4 ap0 = *(const float4*)(att + (size_t)j0 * 8);
            float4 ap1 = *(const float4*)(att + (size_t)j1 * 8);
            unsigned int g0 = *(const unsigned int*)(h2q + (size_t)j0 * 64 + fq * 4);
            unsigned int g1 = *(const unsigned int*)(h2q + (size_t)j1 * 64 + fq * 4);
            float w00 = m0 * __expf(lrelu(ap0.x + ad.x));
            float w01 = m0 * __expf(lrelu(ap0.y + ad.y));
            float w02 = m0 * __expf(lrelu(ap0.z + ad.z));
            float w03 = m0 * __expf(lrelu(ap0.w + ad.w));
            float w10 = m1 * __expf(lrelu(ap1.x + ad.x));
            float w11 = m1 * __expf(lrelu(ap1.y + ad.y));
            float w12 = m1 * __expf(lrelu(ap1.z + ad.z));
            float w13 = m1 * __expf(lrelu(ap1.w + ad.w));
            s[0] += w00 + w10; s[1] += w01 + w11; s[2] += w02 + w12; s[3] += w03 + w13;
            #pragma unroll
            for (int q = 0; q < 4; ++q) {
                float x0 = q2f((g0 >> (q * 8)) & 0xffu);
                float x1 = q2f((g1 >> (q * 8)) & 0xffu);
                acc[0][q] = fmaf(w00, x0, fmaf(w10, x1, acc[0][q]));
                acc[1][q] = fmaf(w01, x0, fmaf(w11, x1, acc[1][q]));
                acc[2][q] = fmaf(w02, x0, fmaf(w12, x1, acc[2][q]));
                acc[3][q] = fmaf(w03, x0, fmaf(w13, x1, acc[3][q]));
            }
            j0 = j2; m0 = m2; j1 = j3; m1 = m3; p += 8;
        }
        #pragma unroll
        for (int h = 0; h < 4; ++h) {
            s[h] += __shfl_xor(s[h], 16);
            s[h] += __shfl_xor(s[h], 32);
            #pragma unroll
            for (int q = 0; q < 4; ++q) {
                acc[h][q] += __shfl_xor(acc[h][q], 16);
                acc[h][q] += __shfl_xor(acc[h][q], 32);
            }
        }
        if (lane < 16) {
            unsigned short* op = oagg + (size_t)i * 256 + fq * 4;
            #pragma unroll
            for (int h = 0; h < 4; ++h) {
                float r = 1.f / s[h];
                uint2 o;
                o.x = f2b(acc[h][0] * r) | (f2b(acc[h][1] * r) << 16);
                o.y = f2b(acc[h][2] * r) | (f2b(acc[h][3] * r) << 16);
                *(uint2*)(op + h * 64) = o;
            }
        }
    }
}

// ---------------- launch ----------------
extern "C" void kernel_launch(void* const* d_in, const int* in_sizes, int n_in,
                              void* d_out, int out_size, void* d_ws, size_t ws_size,
                              hipStream_t stream) {
    const float* x       = (const float*)d_in[0];
    const int*   ei      = (const int*)d_in[1];
    const float* W1l     = (const float*)d_in[2];
    const float* b1l     = (const float*)d_in[3];
    const float* W1r     = (const float*)d_in[4];
    const float* W2l     = (const float*)d_in[5];
    const float* b2l     = (const float*)d_in[6];
    const float* W2r     = (const float*)d_in[7];
    const float* g1      = (const float*)d_in[8];
    const float* be1     = (const float*)d_in[9];
    const float* g2      = (const float*)d_in[10];
    const float* be2     = (const float*)d_in[11];
    const float* Wg      = (const float*)d_in[12];
    const float* att_src = (const float*)d_in[13];
    const float* att_dst = (const float*)d_in[14];
    const float* bg      = (const float*)d_in[15];
    float* out = (float*)d_out;

    char* p = (char*)d_ws;
    auto alloc = [&](size_t bytes) -> char* {
        char* q = p;
        p += (bytes + 255) & ~(size_t)255;
        return q;
    };
    int*   cnt    = (int*)alloc((size_t)N_NODES * 4);
    float* stats  = (float*)alloc(3072 * 4);
    int*   rowptr = (int*)alloc((size_t)(N_NODES + 1) * 4);
    int*   bsums  = (int*)alloc(256 * 4);
    int*   col    = (int*)alloc((size_t)N_EDGES * 4);
    unsigned short* xb  = (unsigned short*)alloc((size_t)N_NODES * 128 * 2);   // 7.68MB (GEMM A2)
    unsigned char*  xq  = (unsigned char*)alloc((size_t)N_NODES * 128);        // 3.84MB (gather, fp8)
    unsigned short* agg1b = (unsigned short*)alloc((size_t)N_NODES * 128 * 2); // 7.68MB
    unsigned short* h1b = (unsigned short*)alloc((size_t)N_NODES * 256 * 2);   // 15.36MB
    unsigned char*  zq  = (unsigned char*)alloc((size_t)N_NODES * 64);         // 1.92MB (gather, fp8)
    unsigned short* r2  = (unsigned short*)alloc((size_t)N_NODES * 64 * 2);    // 3.84MB
    unsigned short* h2  = (unsigned short*)alloc((size_t)N_NODES * 64 * 2);    // 3.84MB (bf16)
    unsigned char*  h2q = (unsigned char*)alloc((size_t)N_NODES * 64);         // 1.92MB (gather, fp8)
    float* att  = (float*)alloc((size_t)N_NODES * 8 * 4);                      // 0.96MB
    unsigned short* w1lt = (unsigned short*)alloc(128 * 256 * 2);
    unsigned short* w1rt = (unsigned short*)alloc(128 * 256 * 2);
    unsigned short* w2lt = (unsigned short*)alloc(256 * 64 * 2);  // [w2lt|w2rt] contiguous [128][256]
    unsigned short* w2rt = (unsigned short*)alloc(256 * 64 * 2);
    unsigned short* btf  = (unsigned short*)alloc(64 * 256 * 2);

    // oagg [N][256] bf16 (15.36MB) aliases xb+xq+agg1b (all dead before k_gat2)
    unsigned short* oagg = xb;

    float* sum1 = stats;              // 4 x 256
    float* sq1  = stats + 1024;       // 4 x 256
    float* sum2 = stats + 2048;       // 4 x 64
    float* sq2  = stats + 2304;       // 4 x 64
    float* vsrc = stats + 2560;
    float* vdst = stats + 2816;

    const int* srcA = ei;
    const int* dstA = ei + N_EDGES;

    k_prep<<<1567, 256, 0, stream>>>(cnt, stats, out, x, xb, xq, W1l, W1r, W2l, W2r, Wg,
                                     w1lt, w1rt, w2lt, w2rt, btf, att_src, att_dst, vsrc, vdst);
    k_count<<<1172, 256, 0, stream>>>(dstA, cnt);
    k_scan1<<<118, 256, 0, stream>>>(cnt, rowptr, bsums);
    k_scan3<<<118, 256, 0, stream>>>(rowptr, bsums, cnt);
    k_fill<<<1172, 256, 0, stream>>>(srcA, dstA, rowptr, cnt, col);

    // SAGE layer 1
    k_sage_agg_q<<<7500, 256, 0, stream>>>(xq, rowptr, col, agg1b);
    k_mgemm<1, false, true><<<dim3(469, 4), 256, 0, stream>>>(
        agg1b, w1lt, 128, xb, w1rt, 128, b1l, h1b, nullptr, nullptr, N_NODES, 256,
        nullptr, nullptr, nullptr, nullptr, sum1, sq1);

    // SAGE layer 2
    k_mgemm<2, true, false><<<dim3(469, 2), 256, 0, stream>>>(
        h1b, w2lt, 256, nullptr, nullptr, 0, nullptr, nullptr, zq, r2, N_NODES, 128,
        sum1, sq1, g1, be1, nullptr, nullptr);
    k_sage_add<<<1875, 256, 0, stream>>>(zq, r2, rowptr, col, b2l, h2, sum2, sq2);

    // GAT
    k_attn2<<<1875, 256, 0, stream>>>(h2, sum2, sq2, g2, be2, vsrc, vdst, h2q, att);
    k_gat2<<<2048, 256, 0, stream>>>(h2q, att, rowptr, col, oagg);
    k_mgemm_mean<<<469, 256, 0, stream>>>(oagg, btf, bg, out, N_NODES);
}